// Round 6
// baseline (135.432 us; speedup 1.0000x reference)
//
#include <hip/hip_runtime.h>

#define HM_B 32
#define HM_C 98
#define HM_H 128
#define HM_W 128
#define HWSZ (HM_H * HM_W)          // 16384
#define HALF (HWSZ / 2)             // 8192 floats per half-row block
#define FDIM 256
#define DDIM 128
#define NODE_F (2 + 1 + FDIM)       // 259
#define NODE_P 260                  // padded LDS row stride
#define BC (HM_B * HM_C)            // 3136
#define HM_ELEMS ((size_t)BC * HWSZ)
#define LCHUNK 8                    // landmarks per embed block (392 blocks)
#define ICHUNK 7                    // rows per gcn block (448 blocks)
#define NTHR 256

typedef float f32x4 __attribute__((ext_vector_type(4)));

// Kernel 1: half-row copy + partial argmax (first occurrence).
// 6272 blocks (2 per landmark row) -> 24.5 blocks/CU, ~2% tail imbalance.
// Plain (temporal) loads/stores: hm is 205 MB < 256 MB L3 and re-read every
// replay; stores are absorbed by writeback L3.
__global__ __launch_bounds__(NTHR) void k1_copy_argmax(
    const float* __restrict__ hm, float* __restrict__ out_hm,
    float* __restrict__ pconf, int* __restrict__ pidx) {
    const int bid = blockIdx.x;
    const int row = bid >> 1;
    const int half = bid & 1;
    const int tid = threadIdx.x;
    const size_t base = (size_t)row * HWSZ + (size_t)half * HALF;
    const f32x4* __restrict__ src = (const f32x4*)(hm + base);
    f32x4* __restrict__ dst = (f32x4*)(out_hm + base);

    float bv = -INFINITY;
    int bi = 0;
    #pragma unroll
    for (int t = 0; t < HALF / 4 / NTHR; ++t) {     // 8 iters
        const int p = t * NTHR + tid;
        const f32x4 v = src[p];
        dst[p] = v;
        const float m4 = fmaxf(fmaxf(v[0], v[1]), fmaxf(v[2], v[3]));
        if (m4 > bv) {  // in-order scan keeps first occurrence within thread
            const int gbase = half * HALF + p * 4;
            if (v[0] > bv) { bv = v[0]; bi = gbase; }
            if (v[1] > bv) { bv = v[1]; bi = gbase + 1; }
            if (v[2] > bv) { bv = v[2]; bi = gbase + 2; }
            if (v[3] > bv) { bv = v[3]; bi = gbase + 3; }
        }
    }

    // wave butterfly reduce: (max value, min index on tie) is associative
    #pragma unroll
    for (int s = 1; s < 64; s <<= 1) {
        const float ov = __shfl_xor(bv, s, 64);
        const int oi = __shfl_xor(bi, s, 64);
        if (ov > bv || (ov == bv && oi < bi)) { bv = ov; bi = oi; }
    }

    __shared__ float wv[NTHR / 64];
    __shared__ int wi[NTHR / 64];
    if ((tid & 63) == 0) { wv[tid >> 6] = bv; wi[tid >> 6] = bi; }
    __syncthreads();
    if (tid == 0) {
        float fv = wv[0]; int fi = wi[0];
        #pragma unroll
        for (int w = 1; w < NTHR / 64; ++w)
            if (wv[w] > fv || (wv[w] == fv && wi[w] < fi)) { fv = wv[w]; fi = wi[w]; }
        pconf[bid] = fv; pidx[bid] = fi;
    }
}

// Kernel 2: combine half-row partials, gather features, embed.
// h0[bc,d] = relu(node . W_embed[:,d] + b_embed[d])
__global__ __launch_bounds__(NTHR) void k2_embed(
    const float* __restrict__ feat, const float* __restrict__ pconf,
    const int* __restrict__ pidx, const float* __restrict__ W_embed,
    const float* __restrict__ b_embed, float* __restrict__ h0_ws) {
    const int bc0 = blockIdx.x * LCHUNK;
    const int tid = threadIdx.x;
    __shared__ float node_s[LCHUNK][NODE_P];   // 8*260*4 = 8320 B
    __shared__ int locs[LCHUNK];

    if (tid < LCHUNK) {
        const int row = bc0 + tid;
        const float v0 = pconf[2 * row];
        const float v1 = pconf[2 * row + 1];
        // half-0 indices all precede half-1 indices: strict > keeps first occ.
        const int loc = (v1 > v0) ? pidx[2 * row + 1] : pidx[2 * row];
        locs[tid] = loc;
        node_s[tid][0] = (float)(loc % HM_W) * (1.0f / (float)HM_H);  // ref: [xs,ys]/[H,W]
        node_s[tid][1] = (float)(loc / HM_W) * (1.0f / (float)HM_W);
        node_s[tid][2] = fmaxf(v0, v1);
    }
    __syncthreads();

    #pragma unroll
    for (int l = 0; l < LCHUNK; ++l) {
        const int bcL = bc0 + l;
        const int bb = bcL / HM_C;            // rows may span batch boundary
        node_s[l][3 + tid] = feat[((size_t)(bb * FDIM + tid)) * HWSZ + locs[l]];
    }
    __syncthreads();

    const int d = tid & (DDIM - 1);
    const int lbase = (tid >> 7) * 4;
    const float bias = b_embed[d];
    float a0 = bias, a1 = bias, a2 = bias, a3 = bias;
    for (int f = 0; f < NODE_F; ++f) {
        const float w = W_embed[f * DDIM + d];
        a0 = fmaf(node_s[lbase + 0][f], w, a0);
        a1 = fmaf(node_s[lbase + 1][f], w, a1);
        a2 = fmaf(node_s[lbase + 2][f], w, a2);
        a3 = fmaf(node_s[lbase + 3][f], w, a3);
    }
    h0_ws[(size_t)(bc0 + lbase + 0) * DDIM + d] = fmaxf(a0, 0.f);
    h0_ws[(size_t)(bc0 + lbase + 1) * DDIM + d] = fmaxf(a1, 0.f);
    h0_ws[(size_t)(bc0 + lbase + 2) * DDIM + d] = fmaxf(a2, 0.f);
    h0_ws[(size_t)(bc0 + lbase + 3) * DDIM + d] = fmaxf(a3, 0.f);
}

// Kernel 3: h1 = relu((A @ h0) @ W_gcn); out2 = h1 @ W_out + b_out.
__global__ __launch_bounds__(DDIM) void k3_gcn(
    const float* __restrict__ A, const float* __restrict__ h0_ws,
    const float* __restrict__ W_gcn, const float* __restrict__ W_out,
    const float* __restrict__ b_out, float* __restrict__ out2) {
    const int b = blockIdx.x / (HM_C / ICHUNK);
    const int i0 = (blockIdx.x % (HM_C / ICHUNK)) * ICHUNK;
    const int tid = threadIdx.x;           // = d

    __shared__ float arow[ICHUNK * HM_C];  // 2744 B
    __shared__ float tmp_s[ICHUNK * DDIM]; // 3584 B
    __shared__ float h1_s[ICHUNK * DDIM];  // 3584 B

    for (int k = tid; k < ICHUNK * HM_C; k += DDIM)
        arow[k] = A[(i0 + k / HM_C) * HM_C + (k % HM_C)];
    __syncthreads();

    {
        float acc[ICHUNK];
        #pragma unroll
        for (int i = 0; i < ICHUNK; ++i) acc[i] = 0.f;
        for (int j = 0; j < HM_C; ++j) {
            const float v = h0_ws[((size_t)b * HM_C + j) * DDIM + tid];
            #pragma unroll
            for (int i = 0; i < ICHUNK; ++i)
                acc[i] = fmaf(arow[i * HM_C + j], v, acc[i]);
        }
        #pragma unroll
        for (int i = 0; i < ICHUNK; ++i) tmp_s[i * DDIM + tid] = acc[i];
    }
    __syncthreads();

    {
        float acc[ICHUNK];
        #pragma unroll
        for (int i = 0; i < ICHUNK; ++i) acc[i] = 0.f;
        for (int k = 0; k < DDIM; ++k) {
            const float w = W_gcn[k * DDIM + tid];
            #pragma unroll
            for (int i = 0; i < ICHUNK; ++i)
                acc[i] = fmaf(tmp_s[i * DDIM + k], w, acc[i]);
        }
        #pragma unroll
        for (int i = 0; i < ICHUNK; ++i) h1_s[i * DDIM + tid] = fmaxf(acc[i], 0.f);
    }
    __syncthreads();

    if (tid < ICHUNK * 2) {
        const int i = tid >> 1;
        const int o = tid & 1;
        float acc = b_out[o];
        for (int dd = 0; dd < DDIM; ++dd)
            acc = fmaf(h1_s[i * DDIM + dd], W_out[dd * 2 + o], acc);
        out2[((size_t)b * HM_C + i0 + i) * 2 + o] = acc;
    }
}

extern "C" void kernel_launch(void* const* d_in, const int* in_sizes, int n_in,
                              void* d_out, int out_size, void* d_ws, size_t ws_size,
                              hipStream_t stream) {
    const float* hm      = (const float*)d_in[0];
    const float* feat    = (const float*)d_in[1];
    const float* W_embed = (const float*)d_in[2];
    const float* b_embed = (const float*)d_in[3];
    const float* A       = (const float*)d_in[4];
    const float* W_gcn   = (const float*)d_in[5];
    const float* W_out   = (const float*)d_in[6];
    const float* b_out   = (const float*)d_in[7];

    float* out_hm = (float*)d_out;                 // [B,C,H,W] passthrough
    float* out2   = (float*)d_out + HM_ELEMS;      // [B,C,2]

    char* ws = (char*)d_ws;
    float* pconf = (float*)ws;  ws += 2 * BC * sizeof(float);
    int*   pidx  = (int*)ws;    ws += 2 * BC * sizeof(int);
    float* h0_ws = (float*)ws;  // BC*128*4 = 1.606 MB; total ~1.66 MB

    k1_copy_argmax<<<2 * BC, NTHR, 0, stream>>>(hm, out_hm, pconf, pidx);
    k2_embed<<<BC / LCHUNK, NTHR, 0, stream>>>(feat, pconf, pidx,
                                               W_embed, b_embed, h0_ws);
    k3_gcn<<<HM_B * (HM_C / ICHUNK), DDIM, 0, stream>>>(A, h0_ws, W_gcn,
                                                        W_out, b_out, out2);
}